// Round 1
// baseline (823.662 us; speedup 1.0000x reference)
//
#include <hip/hip_runtime.h>
#include <math.h>

// Problem constants
#define T_SEQ 2048
#define D_MODEL 3072
#define NQ 16
#define NKV 8
#define HD 256
#define NHEADS_TOT 32          // 16 q + 8 k + 8 v projection "slots"
#define QKV_COLS 8192          // 32 * 256
#define SOFT_CAP 50.0f
#define WINDOW 1024
#define K_MASK -2.3819763e38f

typedef __attribute__((ext_vector_type(8))) short bf16x8;
typedef __attribute__((ext_vector_type(4))) float f32x4;

__device__ __forceinline__ unsigned short f2bf(float f) {
    union { float f; unsigned u; } v; v.f = f;
    unsigned r = (v.u + 0x7fff + ((v.u >> 16) & 1)) >> 16;
    return (unsigned short)r;
}
__device__ __forceinline__ float bf2f(unsigned short u) {
    union { unsigned u; float f; } v; v.u = ((unsigned)u) << 16;
    return v.f;
}

__device__ __forceinline__ void gl_lds16(const unsigned short* g, unsigned short* l) {
    __builtin_amdgcn_global_load_lds(
        (const __attribute__((address_space(1))) void*)g,
        (__attribute__((address_space(3))) void*)l, 16, 0, 0);
}

// ---------------- convert f32 -> bf16 (flat) ----------------
__global__ __launch_bounds__(256) void k_convert(const float* __restrict__ src,
                                                 unsigned short* __restrict__ dst, int n4) {
    int i = blockIdx.x * 256 + threadIdx.x;
    if (i >= n4) return;
    float4 v = ((const float4*)src)[i];
    ushort4 o;
    o.x = f2bf(v.x); o.y = f2bf(v.y); o.z = f2bf(v.z); o.w = f2bf(v.w);
    ((ushort4*)dst)[i] = o;
}

// ---------------- batched transpose+convert: (batch,R,C) f32 -> (batch,C,R) bf16 ----------------
__global__ __launch_bounds__(256) void k_transpose_bf16(const float* __restrict__ src,
                                                        unsigned short* __restrict__ dst,
                                                        int R, int C) {
    __shared__ float tile[32][33];
    int b = blockIdx.z;
    src += (size_t)b * R * C;
    dst += (size_t)b * R * C;
    int c0 = blockIdx.x * 32, r0 = blockIdx.y * 32;
    int tx = threadIdx.x, ty = threadIdx.y;   // 32 x 8
    #pragma unroll
    for (int i = ty; i < 32; i += 8)
        tile[i][tx] = src[(size_t)(r0 + i) * C + c0 + tx];
    __syncthreads();
    #pragma unroll
    for (int i = ty; i < 32; i += 8)
        dst[(size_t)(c0 + i) * R + r0 + tx] = f2bf(tile[tx][i]);
}

// ---------------- NT GEMM: C[M,N] = A[M,K] * BT[N,K]^T   (bf16 in, f32 acc) ----------------
// 128x128 block tile, BK=32, 4 waves each 64x64, global_load_lds staging.
template <int OUT_BF16>
__global__ __launch_bounds__(256) void k_gemm_nt(const unsigned short* __restrict__ A,
                                                 const unsigned short* __restrict__ BT,
                                                 void* __restrict__ Cout,
                                                 int M, int N, int Kd) {
    __shared__ unsigned short As[128 * 32];
    __shared__ unsigned short Bs[128 * 32];
    const int tid = threadIdx.x;
    const int wave = tid >> 6, lane = tid & 63;
    const int col = lane & 15, quad = lane >> 4;
    const int wr = wave >> 1, wc = wave & 1;
    const int m0 = blockIdx.x * 128, n0 = blockIdx.y * 128;
    const int rsel = lane >> 2, csel = lane & 3;

    f32x4 acc[4][4];
    #pragma unroll
    for (int i = 0; i < 4; i++)
        #pragma unroll
        for (int j = 0; j < 4; j++)
            acc[i][j] = (f32x4){0.f, 0.f, 0.f, 0.f};

    const unsigned short* Ab = A + (size_t)m0 * Kd;
    const unsigned short* Bb = BT + (size_t)n0 * Kd;

    for (int k0 = 0; k0 < Kd; k0 += 32) {
        if (wave < 2) {
            #pragma unroll
            for (int s = 0; s < 4; s++) {
                int seg = wave * 4 + s;
                gl_lds16(Ab + (size_t)(seg * 16 + rsel) * Kd + k0 + csel * 8,
                         &As[seg * 16 * 32]);
            }
        } else {
            #pragma unroll
            for (int s = 0; s < 4; s++) {
                int seg = (wave - 2) * 4 + s;
                gl_lds16(Bb + (size_t)(seg * 16 + rsel) * Kd + k0 + csel * 8,
                         &Bs[seg * 16 * 32]);
            }
        }
        __syncthreads();
        bf16x8 af[4], bfr[4];
        #pragma unroll
        for (int i = 0; i < 4; i++)
            af[i] = *(const bf16x8*)&As[(wr * 64 + i * 16 + col) * 32 + quad * 8];
        #pragma unroll
        for (int j = 0; j < 4; j++)
            bfr[j] = *(const bf16x8*)&Bs[(wc * 64 + j * 16 + col) * 32 + quad * 8];
        #pragma unroll
        for (int i = 0; i < 4; i++)
            #pragma unroll
            for (int j = 0; j < 4; j++)
                acc[i][j] = __builtin_amdgcn_mfma_f32_16x16x32_bf16(af[i], bfr[j], acc[i][j], 0, 0, 0);
        __syncthreads();
    }

    #pragma unroll
    for (int i = 0; i < 4; i++) {
        int row = m0 + wr * 64 + i * 16 + quad * 4;
        #pragma unroll
        for (int j = 0; j < 4; j++) {
            int c = n0 + wc * 64 + j * 16 + col;
            #pragma unroll
            for (int r = 0; r < 4; r++) {
                float v = acc[i][j][r];
                if (OUT_BF16)
                    ((unsigned short*)Cout)[(size_t)(row + r) * N + c] = f2bf(v);
                else
                    ((float*)Cout)[(size_t)(row + r) * N + c] = v;
            }
        }
    }
}

// ---------------- RMS-norm (+scale) + RoPE, scatter to attention layouts ----------------
// qkv: (T, 8192) bf16.  slots: 0..15 q heads, 16..23 k heads, 24..31 v heads.
// q -> qh[n][t][h]; k -> kh[kk][t][h]; v -> vT[kk][h][t]  (all bf16)
__global__ __launch_bounds__(256) void k_norm_rope(const unsigned short* __restrict__ qkv,
                                                   const int* __restrict__ spos,
                                                   const float* __restrict__ qscale,
                                                   const float* __restrict__ kscale,
                                                   unsigned short* __restrict__ qh,
                                                   unsigned short* __restrict__ kh,
                                                   unsigned short* __restrict__ vT) {
    const int t = blockIdx.x, slot = blockIdx.y, h = threadIdx.x;
    float val = bf2f(qkv[(size_t)t * QKV_COLS + slot * HD + h]);
    float ss = val * val;
    #pragma unroll
    for (int m = 1; m < 64; m <<= 1) ss += __shfl_xor(ss, m, 64);
    __shared__ float wsum[4];
    __shared__ float ybuf[256];
    if ((h & 63) == 0) wsum[h >> 6] = ss;
    __syncthreads();
    float tot = wsum[0] + wsum[1] + wsum[2] + wsum[3];
    float y = val * rsqrtf(tot * (1.0f / 256.0f) + 1e-6f);
    if (slot < 16) y *= (1.0f + qscale[h]);
    else if (slot < 24) y *= (1.0f + kscale[h]);

    if (slot < 24) {
        ybuf[h] = y;
        __syncthreads();
        int hh = h & 127;
        float fr = (float)hh * (1.0f / 128.0f);
        float ts = powf(10000.0f, fr);
        float ang = (float)spos[t] / ts;
        float sn = sinf(ang), cs = cosf(ang);
        float other = ybuf[(h < 128) ? (h + 128) : (h - 128)];
        float outv = (h < 128) ? (y * cs - other * sn) : (y * cs + other * sn);
        if (slot < 16)
            qh[((size_t)slot * T_SEQ + t) * HD + h] = f2bf(outv);
        else
            kh[((size_t)(slot - 16) * T_SEQ + t) * HD + h] = f2bf(outv);
    } else {
        vT[((size_t)(slot - 24) * HD + h) * T_SEQ + t] = f2bf(y);
    }
}

// ---------------- flash attention: 1 wave per (q head, 16-row q tile) ----------------
__global__ __launch_bounds__(64) void k_attn(const unsigned short* __restrict__ qh,
                                             const unsigned short* __restrict__ kh,
                                             const unsigned short* __restrict__ vT,
                                             unsigned short* __restrict__ enc) {
    __shared__ unsigned short Pl[16 * 32];
    const int lane = threadIdx.x;
    const int col = lane & 15, quad = lane >> 4;
    const int tile = blockIdx.x, n = blockIdx.y;
    const int t0 = tile * 16, kk = n >> 1;
    const unsigned short* qp = qh + ((size_t)n * T_SEQ + t0) * HD;
    const unsigned short* kp = kh + (size_t)kk * T_SEQ * HD;
    const unsigned short* vp = vT + (size_t)kk * HD * T_SEQ;

    bf16x8 qf[8];
    #pragma unroll
    for (int c = 0; c < 8; c++)
        qf[c] = *(const bf16x8*)(qp + (size_t)col * HD + c * 32 + quad * 8);

    f32x4 o[16];
    #pragma unroll
    for (int h = 0; h < 16; h++) o[h] = (f32x4){0.f, 0.f, 0.f, 0.f};
    float mrow[4] = {-3.402823466e38f, -3.402823466e38f, -3.402823466e38f, -3.402823466e38f};
    float lrow[4] = {0.f, 0.f, 0.f, 0.f};

    int s_begin = t0 - (WINDOW - 1);
    if (s_begin < 0) s_begin = 0;
    s_begin &= ~31;

    for (int s0 = s_begin; s0 < t0 + 16; s0 += 32) {
        f32x4 S0 = (f32x4){0.f, 0.f, 0.f, 0.f};
        f32x4 S1 = (f32x4){0.f, 0.f, 0.f, 0.f};
        #pragma unroll
        for (int c = 0; c < 8; c++) {
            bf16x8 b0 = *(const bf16x8*)(kp + (size_t)(s0 + col) * HD + c * 32 + quad * 8);
            S0 = __builtin_amdgcn_mfma_f32_16x16x32_bf16(qf[c], b0, S0, 0, 0, 0);
        }
        #pragma unroll
        for (int c = 0; c < 8; c++) {
            bf16x8 b1 = *(const bf16x8*)(kp + (size_t)(s0 + 16 + col) * HD + c * 32 + quad * 8);
            S1 = __builtin_amdgcn_mfma_f32_16x16x32_bf16(qf[c], b1, S1, 0, 0, 0);
        }

        float p0[4], p1[4], alpha[4];
        #pragma unroll
        for (int r = 0; r < 4; r++) {
            int t = t0 + quad * 4 + r;
            int sA = s0 + col, sB = s0 + 16 + col;
            bool vA = (sA <= t) && (sA >= t - (WINDOW - 1));
            bool vB = (sB <= t) && (sB >= t - (WINDOW - 1));
            float xA = vA ? tanhf(S0[r] * (1.0f / SOFT_CAP)) * SOFT_CAP : K_MASK;
            float xB = vB ? tanhf(S1[r] * (1.0f / SOFT_CAP)) * SOFT_CAP : K_MASK;
            float mt = fmaxf(xA, xB);
            #pragma unroll
            for (int msk = 1; msk < 16; msk <<= 1)
                mt = fmaxf(mt, __shfl_xor(mt, msk, 16));
            float mn = fmaxf(mrow[r], mt);
            alpha[r] = expf(mrow[r] - mn);
            p0[r] = vA ? expf(xA - mn) : 0.0f;
            p1[r] = vB ? expf(xB - mn) : 0.0f;
            float rs = p0[r] + p1[r];
            #pragma unroll
            for (int msk = 1; msk < 16; msk <<= 1)
                rs += __shfl_xor(rs, msk, 16);
            lrow[r] = lrow[r] * alpha[r] + rs;
            mrow[r] = mn;
        }

        #pragma unroll
        for (int h = 0; h < 16; h++)
            #pragma unroll
            for (int r = 0; r < 4; r++)
                o[h][r] *= alpha[r];

        __syncthreads();
        #pragma unroll
        for (int r = 0; r < 4; r++) {
            Pl[(quad * 4 + r) * 32 + col] = f2bf(p0[r]);
            Pl[(quad * 4 + r) * 32 + 16 + col] = f2bf(p1[r]);
        }
        __syncthreads();

        bf16x8 pf = *(const bf16x8*)&Pl[col * 32 + quad * 8];
        #pragma unroll
        for (int h = 0; h < 16; h++) {
            bf16x8 vf = *(const bf16x8*)(vp + (size_t)(h * 16 + col) * T_SEQ + s0 + quad * 8);
            o[h] = __builtin_amdgcn_mfma_f32_16x16x32_bf16(pf, vf, o[h], 0, 0, 0);
        }
    }

    #pragma unroll
    for (int r = 0; r < 4; r++) {
        float inv = 1.0f / lrow[r];
        int t = t0 + quad * 4 + r;
        #pragma unroll
        for (int h = 0; h < 16; h++)
            enc[(size_t)t * (NQ * HD) + n * HD + h * 16 + col] = f2bf(o[h][r] * inv);
    }
}

extern "C" void kernel_launch(void* const* d_in, const int* in_sizes, int n_in,
                              void* d_out, int out_size, void* d_ws, size_t ws_size,
                              hipStream_t stream) {
    const float* x       = (const float*)d_in[0];
    const int*   spos    = (const int*)d_in[1];
    // d_in[2] attn_mask: known tril(causal); handled analytically
    const float* w_q     = (const float*)d_in[3];
    const float* w_kv    = (const float*)d_in[4];
    const float* w_out   = (const float*)d_in[5];
    const float* q_scale = (const float*)d_in[6];
    const float* k_scale = (const float*)d_in[7];
    float* out = (float*)d_out;

    char* ws = (char*)d_ws;
    // layout (bytes):
    unsigned short* xb     = (unsigned short*)(ws + 0);          // 2048x3072 bf16  (12582912 B)
    unsigned short* wT     = (unsigned short*)(ws + 12582912);   // 8192x3072 bf16  (50331648 B)
    unsigned short* wToutb = (unsigned short*)(ws + 12582912);   // 3072x4096 bf16  (reuse after gemm1)
    unsigned short* encb   = (unsigned short*)(ws + 37748736);   // 2048x4096 bf16  (reuse after gemm1)
    unsigned short* qkv    = (unsigned short*)(ws + 62914560);   // 2048x8192 bf16  (33554432 B)
    unsigned short* qh     = (unsigned short*)(ws + 96468992);   // 16x2048x256 bf16
    unsigned short* kh     = (unsigned short*)(ws + 113246208);  // 8x2048x256 bf16
    unsigned short* vT     = (unsigned short*)(ws + 121634816);  // 8x256x2048 bf16
    // total: 130023424 B

    // 1. x -> bf16
    k_convert<<<dim3((T_SEQ * D_MODEL / 4 + 255) / 256), dim3(256), 0, stream>>>(
        x, xb, T_SEQ * D_MODEL / 4);
    // 2. w_q: 16 x (3072x256) -> (256x3072) into wT rows [0,4096)
    k_transpose_bf16<<<dim3(HD / 32, D_MODEL / 32, NQ), dim3(32, 8), 0, stream>>>(
        w_q, wT, D_MODEL, HD);
    // 3. w_kv: 16 x (3072x256) -> rows [4096,8192)
    k_transpose_bf16<<<dim3(HD / 32, D_MODEL / 32, 16), dim3(32, 8), 0, stream>>>(
        w_kv, wT + (size_t)4096 * D_MODEL, D_MODEL, HD);
    // 4. QKV projection GEMM -> qkv (bf16)
    k_gemm_nt<1><<<dim3(T_SEQ / 128, QKV_COLS / 128), dim3(256), 0, stream>>>(
        xb, wT, qkv, T_SEQ, QKV_COLS, D_MODEL);
    // 5. w_out: (4096x3072) -> (3072x4096) (reuses wT space; stream-ordered after gemm1)
    k_transpose_bf16<<<dim3(D_MODEL / 32, 4096 / 32, 1), dim3(32, 8), 0, stream>>>(
        w_out, wToutb, 4096, D_MODEL);
    // 6. norm + rope
    k_norm_rope<<<dim3(T_SEQ, NHEADS_TOT), dim3(256), 0, stream>>>(
        qkv, spos, q_scale, k_scale, qh, kh, vT);
    // 7. attention
    k_attn<<<dim3(T_SEQ / 16, NQ), dim3(64), 0, stream>>>(qh, kh, vT, encb);
    // 8. output projection
    k_gemm_nt<0><<<dim3(T_SEQ / 128, D_MODEL / 128), dim3(256), 0, stream>>>(
        encb, wToutb, out, T_SEQ, D_MODEL, NQ * HD);
}

// Round 2
// 618.810 us; speedup vs baseline: 1.3310x; 1.3310x over previous
//
#include <hip/hip_runtime.h>
#include <math.h>

// Problem constants
#define T_SEQ 2048
#define D_MODEL 3072
#define NQ 16
#define NKV 8
#define HD 256
#define NHEADS_TOT 32          // 16 q + 8 k + 8 v projection "slots"
#define QKV_COLS 8192          // 32 * 256
#define SOFT_CAP 50.0f
#define WINDOW 1024
#define K_MASK -2.3819763e38f

typedef __attribute__((ext_vector_type(8))) short bf16x8;
typedef __attribute__((ext_vector_type(4))) float f32x4;

__device__ __forceinline__ unsigned short f2bf(float f) {
    union { float f; unsigned u; } v; v.f = f;
    unsigned r = (v.u + 0x7fff + ((v.u >> 16) & 1)) >> 16;
    return (unsigned short)r;
}
__device__ __forceinline__ float bf2f(unsigned short u) {
    union { unsigned u; float f; } v; v.u = ((unsigned)u) << 16;
    return v.f;
}

__device__ __forceinline__ void gl_lds16(const unsigned short* g, unsigned short* l) {
    __builtin_amdgcn_global_load_lds(
        (const __attribute__((address_space(1))) void*)g,
        (__attribute__((address_space(3))) void*)l, 16, 0, 0);
}

// ---------------- convert f32 -> bf16 (flat) ----------------
__global__ __launch_bounds__(256) void k_convert(const float* __restrict__ src,
                                                 unsigned short* __restrict__ dst, int n4) {
    int i = blockIdx.x * 256 + threadIdx.x;
    if (i >= n4) return;
    float4 v = ((const float4*)src)[i];
    ushort4 o;
    o.x = f2bf(v.x); o.y = f2bf(v.y); o.z = f2bf(v.z); o.w = f2bf(v.w);
    ((ushort4*)dst)[i] = o;
}

// ---------------- batched transpose+convert: (batch,R,C) f32 -> (batch,C,R) bf16 ----------------
__global__ __launch_bounds__(256) void k_transpose_bf16(const float* __restrict__ src,
                                                        unsigned short* __restrict__ dst,
                                                        int R, int C) {
    __shared__ float tile[32][33];
    int b = blockIdx.z;
    src += (size_t)b * R * C;
    dst += (size_t)b * R * C;
    int c0 = blockIdx.x * 32, r0 = blockIdx.y * 32;
    int tx = threadIdx.x, ty = threadIdx.y;   // 32 x 8
    #pragma unroll
    for (int i = ty; i < 32; i += 8)
        tile[i][tx] = src[(size_t)(r0 + i) * C + c0 + tx];
    __syncthreads();
    #pragma unroll
    for (int i = ty; i < 32; i += 8)
        dst[(size_t)(c0 + i) * R + r0 + tx] = f2bf(tile[tx][i]);
}

// ---------------- NT GEMM: C[M,N] = A[M,K] * BT[N,K]^T   (bf16 in, f32 acc) ----------------
template <int OUT_BF16>
__global__ __launch_bounds__(256) void k_gemm_nt(const unsigned short* __restrict__ A,
                                                 const unsigned short* __restrict__ BT,
                                                 void* __restrict__ Cout,
                                                 int M, int N, int Kd) {
    __shared__ unsigned short As[128 * 32];
    __shared__ unsigned short Bs[128 * 32];
    const int tid = threadIdx.x;
    const int wave = tid >> 6, lane = tid & 63;
    const int col = lane & 15, quad = lane >> 4;
    const int wr = wave >> 1, wc = wave & 1;
    const int m0 = blockIdx.x * 128, n0 = blockIdx.y * 128;
    const int rsel = lane >> 2, csel = lane & 3;

    f32x4 acc[4][4];
    #pragma unroll
    for (int i = 0; i < 4; i++)
        #pragma unroll
        for (int j = 0; j < 4; j++)
            acc[i][j] = (f32x4){0.f, 0.f, 0.f, 0.f};

    const unsigned short* Ab = A + (size_t)m0 * Kd;
    const unsigned short* Bb = BT + (size_t)n0 * Kd;

    for (int k0 = 0; k0 < Kd; k0 += 32) {
        if (wave < 2) {
            #pragma unroll
            for (int s = 0; s < 4; s++) {
                int seg = wave * 4 + s;
                gl_lds16(Ab + (size_t)(seg * 16 + rsel) * Kd + k0 + csel * 8,
                         &As[seg * 16 * 32]);
            }
        } else {
            #pragma unroll
            for (int s = 0; s < 4; s++) {
                int seg = (wave - 2) * 4 + s;
                gl_lds16(Bb + (size_t)(seg * 16 + rsel) * Kd + k0 + csel * 8,
                         &Bs[seg * 16 * 32]);
            }
        }
        __syncthreads();
        bf16x8 af[4], bfr[4];
        #pragma unroll
        for (int i = 0; i < 4; i++)
            af[i] = *(const bf16x8*)&As[(wr * 64 + i * 16 + col) * 32 + quad * 8];
        #pragma unroll
        for (int j = 0; j < 4; j++)
            bfr[j] = *(const bf16x8*)&Bs[(wc * 64 + j * 16 + col) * 32 + quad * 8];
        #pragma unroll
        for (int i = 0; i < 4; i++)
            #pragma unroll
            for (int j = 0; j < 4; j++)
                acc[i][j] = __builtin_amdgcn_mfma_f32_16x16x32_bf16(af[i], bfr[j], acc[i][j], 0, 0, 0);
        __syncthreads();
    }

    #pragma unroll
    for (int i = 0; i < 4; i++) {
        int row = m0 + wr * 64 + i * 16 + quad * 4;
        #pragma unroll
        for (int j = 0; j < 4; j++) {
            int c = n0 + wc * 64 + j * 16 + col;
            #pragma unroll
            for (int r = 0; r < 4; r++) {
                float v = acc[i][j][r];
                if (OUT_BF16)
                    ((unsigned short*)Cout)[(size_t)(row + r) * N + c] = f2bf(v);
                else
                    ((float*)Cout)[(size_t)(row + r) * N + c] = v;
            }
        }
    }
}

// ---------------- RMS-norm (+scale) + RoPE, scatter to attention layouts ----------------
__global__ __launch_bounds__(256) void k_norm_rope(const unsigned short* __restrict__ qkv,
                                                   const int* __restrict__ spos,
                                                   const float* __restrict__ qscale,
                                                   const float* __restrict__ kscale,
                                                   unsigned short* __restrict__ qh,
                                                   unsigned short* __restrict__ kh,
                                                   unsigned short* __restrict__ vT) {
    const int t = blockIdx.x, slot = blockIdx.y, h = threadIdx.x;
    float val = bf2f(qkv[(size_t)t * QKV_COLS + slot * HD + h]);
    float ss = val * val;
    #pragma unroll
    for (int m = 1; m < 64; m <<= 1) ss += __shfl_xor(ss, m, 64);
    __shared__ float wsum[4];
    __shared__ float ybuf[256];
    if ((h & 63) == 0) wsum[h >> 6] = ss;
    __syncthreads();
    float tot = wsum[0] + wsum[1] + wsum[2] + wsum[3];
    float y = val * rsqrtf(tot * (1.0f / 256.0f) + 1e-6f);
    if (slot < 16) y *= (1.0f + qscale[h]);
    else if (slot < 24) y *= (1.0f + kscale[h]);

    if (slot < 24) {
        ybuf[h] = y;
        __syncthreads();
        int hh = h & 127;
        float fr = (float)hh * (1.0f / 128.0f);
        float ts = __expf(fr * 9.210340371976184f);   // 10000^fr
        float ang = (float)spos[t] / ts;
        float sn = __sinf(ang), cs = __cosf(ang);
        float other = ybuf[(h < 128) ? (h + 128) : (h - 128)];
        float outv = (h < 128) ? (y * cs - other * sn) : (y * cs + other * sn);
        if (slot < 16)
            qh[((size_t)slot * T_SEQ + t) * HD + h] = f2bf(outv);
        else
            kh[((size_t)(slot - 16) * T_SEQ + t) * HD + h] = f2bf(outv);
    } else {
        vT[((size_t)(slot - 24) * HD + h) * T_SEQ + t] = f2bf(y);
    }
}

// ---------------- flash attention v2 ----------------
// Block: 256 thr = 4 waves. blockIdx.x = kv head (8), blockIdx.y = 32-row t tile (64).
// wave: headSel = w&1 (q head = 2*kk+headSel), rowSel = w>>1 (16-row q subtile).
// K/V tiles staged in LDS once per 32-col step, shared by all 4 waves.
// Softmax with fixed m=0 (logits bounded +-50 by softcap) -> no online max.
__global__ __launch_bounds__(256) void k_attn(const unsigned short* __restrict__ qh,
                                              const unsigned short* __restrict__ kh,
                                              const unsigned short* __restrict__ vT,
                                              unsigned short* __restrict__ enc) {
    __shared__ unsigned short Ks[32 * 256];   // [s][k], 16B granules XOR-swizzled by (s&7)
    __shared__ unsigned short Vs[256 * 32];   // [h][s], 16B granules XOR-swizzled by (h&3)
    __shared__ unsigned short Pl[4][16 * 40]; // per-wave P round-trip, stride 40 kills conflicts

    const int tid = threadIdx.x;
    const int wave = tid >> 6, lane = tid & 63;
    const int col = lane & 15, quad = lane >> 4;
    const int kk = blockIdx.x;
    const int t0b = blockIdx.y * 32;
    const int headSel = wave & 1, rowSel = wave >> 1;
    const int n = kk * 2 + headSel;
    const int tw = t0b + rowSel * 16;

    const unsigned short* qp = qh + ((size_t)n * T_SEQ + tw) * HD;
    const unsigned short* kp = kh + (size_t)kk * T_SEQ * HD;
    const unsigned short* vp = vT + (size_t)kk * HD * T_SEQ;

    // Q fragments (A-operand: row = tw + col, k = c*32 + quad*8)
    bf16x8 qf[8];
    #pragma unroll
    for (int c = 0; c < 8; c++)
        qf[c] = *(const bf16x8*)(qp + (size_t)col * HD + c * 32 + quad * 8);

    // staging offsets (element units), computed once
    int preK[4], preV[4], ldsKo[4], ldsVo[4];
    #pragma unroll
    for (int i = 0; i < 4; i++) {
        int krow = 2 * (wave * 4 + i) + (lane >> 5);
        int kpos = lane & 31;
        preK[i] = krow * HD + ((kpos ^ (krow & 7)) * 8);
        ldsKo[i] = (wave * 4 + i) * 512;
        int vh = (wave * 4 + i) * 16 + (lane >> 2);
        int vpp = lane & 3;
        preV[i] = vh * T_SEQ + ((vpp ^ (vh & 3)) * 8);
        ldsVo[i] = (wave * 4 + i) * 512;
    }

    f32x4 o[16];
    #pragma unroll
    for (int h = 0; h < 16; h++) o[h] = (f32x4){0.f, 0.f, 0.f, 0.f};
    float lsum[4] = {0.f, 0.f, 0.f, 0.f};

    int s_begin = t0b - (WINDOW - 1);
    if (s_begin < 0) s_begin = 0;
    s_begin &= ~31;
    const int s_end = t0b + 32;

    for (int s0 = s_begin; s0 < s_end; s0 += 32) {
        // stage K (32x256) and V (256x32) tiles
        #pragma unroll
        for (int i = 0; i < 4; i++)
            gl_lds16(kp + (size_t)s0 * HD + preK[i], &Ks[ldsKo[i]]);
        #pragma unroll
        for (int i = 0; i < 4; i++)
            gl_lds16(vp + (size_t)s0 + preV[i], &Vs[ldsVo[i]]);
        __syncthreads();

        // QK^T: S tiles for s in [s0,s0+16) and [s0+16,s0+32)
        f32x4 S0 = (f32x4){0.f, 0.f, 0.f, 0.f};
        f32x4 S1 = (f32x4){0.f, 0.f, 0.f, 0.f};
        #pragma unroll
        for (int c = 0; c < 8; c++) {
            bf16x8 kf = *(const bf16x8*)&Ks[(size_t)col * HD + (((c * 4 + quad) ^ (col & 7)) * 8)];
            S0 = __builtin_amdgcn_mfma_f32_16x16x32_bf16(qf[c], kf, S0, 0, 0, 0);
        }
        #pragma unroll
        for (int c = 0; c < 8; c++) {
            bf16x8 kf = *(const bf16x8*)&Ks[(size_t)(16 + col) * HD + (((c * 4 + quad) ^ (col & 7)) * 8)];
            S1 = __builtin_amdgcn_mfma_f32_16x16x32_bf16(qf[c], kf, S1, 0, 0, 0);
        }

        // softcap + exp (m=0): p = exp(50 - 100/(exp(S/25)+1)), masked
        #pragma unroll
        for (int r = 0; r < 4; r++) {
            int t = tw + quad * 4 + r;
            int sA = s0 + col, sB = sA + 16;
            bool vA = (sA <= t) && (sA >= t - (WINDOW - 1));
            bool vB = (sB <= t) && (sB >= t - (WINDOW - 1));
            float eA = __expf(S0[r] * (2.0f / SOFT_CAP));
            float eB = __expf(S1[r] * (2.0f / SOFT_CAP));
            float rA = __builtin_amdgcn_rcpf(eA + 1.0f);
            float rB = __builtin_amdgcn_rcpf(eB + 1.0f);
            float pA = __expf(SOFT_CAP - 2.0f * SOFT_CAP * rA);
            float pB = __expf(SOFT_CAP - 2.0f * SOFT_CAP * rB);
            pA = vA ? pA : 0.0f;
            pB = vB ? pB : 0.0f;
            lsum[r] += pA + pB;
            Pl[wave][(quad * 4 + r) * 40 + col] = f2bf(pA);
            Pl[wave][(quad * 4 + r) * 40 + 16 + col] = f2bf(pB);
        }

        // P back as A-fragment (wave-local LDS round trip; in-wave ordering)
        bf16x8 pf = *(const bf16x8*)&Pl[wave][col * 40 + quad * 8];

        // PV: O[t][h] += P[t][s] * V[s][h], B-operand = V^T from Vs
        #pragma unroll
        for (int ht = 0; ht < 16; ht++) {
            int h = ht * 16 + col;
            bf16x8 vf = *(const bf16x8*)&Vs[(size_t)h * 32 + ((quad ^ (h & 3)) * 8)];
            o[ht] = __builtin_amdgcn_mfma_f32_16x16x32_bf16(pf, vf, o[ht], 0, 0, 0);
        }
        __syncthreads();
    }

    // finalize: reduce l across the 16 cols, normalize, write enc
    #pragma unroll
    for (int r = 0; r < 4; r++) {
        #pragma unroll
        for (int m = 1; m < 16; m <<= 1)
            lsum[r] += __shfl_xor(lsum[r], m, 16);
        lsum[r] = 1.0f / lsum[r];
    }
    #pragma unroll
    for (int ht = 0; ht < 16; ht++) {
        #pragma unroll
        for (int r = 0; r < 4; r++) {
            int t = tw + quad * 4 + r;
            enc[(size_t)t * (NQ * HD) + n * HD + ht * 16 + col] = f2bf(o[ht][r] * lsum[r]);
        }
    }
}

extern "C" void kernel_launch(void* const* d_in, const int* in_sizes, int n_in,
                              void* d_out, int out_size, void* d_ws, size_t ws_size,
                              hipStream_t stream) {
    const float* x       = (const float*)d_in[0];
    const int*   spos    = (const int*)d_in[1];
    const float* w_q     = (const float*)d_in[3];
    const float* w_kv    = (const float*)d_in[4];
    const float* w_out   = (const float*)d_in[5];
    const float* q_scale = (const float*)d_in[6];
    const float* k_scale = (const float*)d_in[7];
    float* out = (float*)d_out;

    char* ws = (char*)d_ws;
    unsigned short* xb     = (unsigned short*)(ws + 0);          // 2048x3072 bf16
    unsigned short* wT     = (unsigned short*)(ws + 12582912);   // 8192x3072 bf16
    unsigned short* wToutb = (unsigned short*)(ws + 12582912);   // 3072x4096 bf16 (reuse)
    unsigned short* encb   = (unsigned short*)(ws + 37748736);   // 2048x4096 bf16 (reuse)
    unsigned short* qkv    = (unsigned short*)(ws + 62914560);   // 2048x8192 bf16
    unsigned short* qh     = (unsigned short*)(ws + 96468992);   // 16x2048x256 bf16
    unsigned short* kh     = (unsigned short*)(ws + 113246208);  // 8x2048x256 bf16
    unsigned short* vT     = (unsigned short*)(ws + 121634816);  // 8x256x2048 bf16

    k_convert<<<dim3((T_SEQ * D_MODEL / 4 + 255) / 256), dim3(256), 0, stream>>>(
        x, xb, T_SEQ * D_MODEL / 4);
    k_transpose_bf16<<<dim3(HD / 32, D_MODEL / 32, NQ), dim3(32, 8), 0, stream>>>(
        w_q, wT, D_MODEL, HD);
    k_transpose_bf16<<<dim3(HD / 32, D_MODEL / 32, 16), dim3(32, 8), 0, stream>>>(
        w_kv, wT + (size_t)4096 * D_MODEL, D_MODEL, HD);
    k_gemm_nt<1><<<dim3(T_SEQ / 128, QKV_COLS / 128), dim3(256), 0, stream>>>(
        xb, wT, qkv, T_SEQ, QKV_COLS, D_MODEL);
    k_transpose_bf16<<<dim3(D_MODEL / 32, 4096 / 32, 1), dim3(32, 8), 0, stream>>>(
        w_out, wToutb, 4096, D_MODEL);
    k_norm_rope<<<dim3(T_SEQ, NHEADS_TOT), dim3(256), 0, stream>>>(
        qkv, spos, q_scale, k_scale, qh, kh, vT);
    k_attn<<<dim3(NKV, T_SEQ / 32), dim3(256), 0, stream>>>(qh, kh, vT, encb);
    k_gemm_nt<0><<<dim3(T_SEQ / 128, D_MODEL / 128), dim3(256), 0, stream>>>(
        encb, wToutb, out, T_SEQ, D_MODEL, NQ * HD);
}

// Round 3
// 558.897 us; speedup vs baseline: 1.4737x; 1.1072x over previous
//
#include <hip/hip_runtime.h>
#include <math.h>

// Problem constants
#define T_SEQ 2048
#define D_MODEL 3072
#define NQ 16
#define NKV 8
#define HD 256
#define NHEADS_TOT 32          // 16 q + 8 k + 8 v projection "slots"
#define QKV_COLS 8192          // 32 * 256
#define SOFT_CAP 50.0f
#define WINDOW 1024
#define K_MASK -2.3819763e38f

typedef __attribute__((ext_vector_type(8))) short bf16x8;
typedef __attribute__((ext_vector_type(4))) float f32x4;

__device__ __forceinline__ unsigned short f2bf(float f) {
    union { float f; unsigned u; } v; v.f = f;
    unsigned r = (v.u + 0x7fff + ((v.u >> 16) & 1)) >> 16;
    return (unsigned short)r;
}
__device__ __forceinline__ float bf2f(unsigned short u) {
    union { unsigned u; float f; } v; v.u = ((unsigned)u) << 16;
    return v.f;
}

__device__ __forceinline__ void gl_lds16(const unsigned short* g, unsigned short* l) {
    __builtin_amdgcn_global_load_lds(
        (const __attribute__((address_space(1))) void*)g,
        (__attribute__((address_space(3))) void*)l, 16, 0, 0);
}

// ---------------- convert f32 -> bf16 (flat) ----------------
__global__ __launch_bounds__(256) void k_convert(const float* __restrict__ src,
                                                 unsigned short* __restrict__ dst, int n4) {
    int i = blockIdx.x * 256 + threadIdx.x;
    if (i >= n4) return;
    float4 v = ((const float4*)src)[i];
    ushort4 o;
    o.x = f2bf(v.x); o.y = f2bf(v.y); o.z = f2bf(v.z); o.w = f2bf(v.w);
    ((ushort4*)dst)[i] = o;
}

// ---------------- batched transpose+convert: (batch,R,C) f32 -> (batch,C,R) bf16 ----------------
__global__ __launch_bounds__(256) void k_transpose_bf16(const float* __restrict__ src,
                                                        unsigned short* __restrict__ dst,
                                                        int R, int C) {
    __shared__ float tile[32][33];
    int b = blockIdx.z;
    src += (size_t)b * R * C;
    dst += (size_t)b * R * C;
    int c0 = blockIdx.x * 32, r0 = blockIdx.y * 32;
    int tx = threadIdx.x, ty = threadIdx.y;   // 32 x 8
    #pragma unroll
    for (int i = ty; i < 32; i += 8)
        tile[i][tx] = src[(size_t)(r0 + i) * C + c0 + tx];
    __syncthreads();
    #pragma unroll
    for (int i = ty; i < 32; i += 8)
        dst[(size_t)(c0 + i) * R + r0 + tx] = f2bf(tile[tx][i]);
}

// ---------------- NT GEMM: C[M,N] = A[M,K] * BT[N,K]^T   (bf16 in, f32 acc) ----------------
// 128x128 block tile, BK=64, 4 waves each 64x64.
// 1-D grid with XCD-aware remap: blocks resident on one XCD share an n-panel (B L2-local).
// LDS layout: row-major [row][k], 16B granules XOR-swizzled by (row&7) -> conflict-free
// frag reads AND valid wave-uniform gl_lds16 destinations.
template <int OUT_BF16>
__global__ __launch_bounds__(256) void k_gemm_nt(const unsigned short* __restrict__ A,
                                                 const unsigned short* __restrict__ BT,
                                                 void* __restrict__ Cout,
                                                 int M, int N, int Kd) {
    __shared__ unsigned short As[128 * 64];
    __shared__ unsigned short Bs[128 * 64];
    const int tid = threadIdx.x;
    const int wave = tid >> 6, lane = tid & 63;
    const int col = lane & 15, quad = lane >> 4;
    const int wr = wave >> 1, wc = wave & 1;

    const int gx = M >> 7;
    int p = blockIdx.x;
    int xcd = p & 7, q = p >> 3;
    int i_t = q % gx, jj = q / gx;
    int j_t = jj * 8 + xcd;
    const int m0 = i_t * 128, n0 = j_t * 128;

    // staging assignment: wave0 -> A rows 0-63, wave1 -> A rows 64-127,
    //                     wave2 -> B rows 0-63, wave3 -> B rows 64-127
    const int sub = wave & 1, isB = wave >> 1;
    const unsigned short* srcBase = isB ? (BT + (size_t)(n0 + sub * 64) * Kd)
                                        : (A + (size_t)(m0 + sub * 64) * Kd);
    unsigned short* ldsBase = (isB ? Bs : As) + sub * 64 * 64;
    const int lrow = lane >> 3, lchk = lane & 7;
    int soff[8];
    #pragma unroll
    for (int s = 0; s < 8; s++) {
        int r = s * 8 + lrow;
        soff[s] = r * Kd + ((lchk ^ (r & 7)) * 8);
    }

    f32x4 acc[4][4];
    #pragma unroll
    for (int i = 0; i < 4; i++)
        #pragma unroll
        for (int j = 0; j < 4; j++)
            acc[i][j] = (f32x4){0.f, 0.f, 0.f, 0.f};

    const int sw = col & 7;   // frag-row swizzle key (rows are col mod 16, &7 = col&7)

    for (int k0 = 0; k0 < Kd; k0 += 64) {
        #pragma unroll
        for (int s = 0; s < 8; s++)
            gl_lds16(srcBase + soff[s] + k0, ldsBase + s * 512);
        __syncthreads();

        #pragma unroll
        for (int kk = 0; kk < 2; kk++) {
            bf16x8 af[4], bfr[4];
            const int chko = ((kk * 4 + quad) ^ sw) * 8;
            #pragma unroll
            for (int i = 0; i < 4; i++)
                af[i] = *(const bf16x8*)&As[(wr * 64 + i * 16 + col) * 64 + chko];
            #pragma unroll
            for (int j = 0; j < 4; j++)
                bfr[j] = *(const bf16x8*)&Bs[(wc * 64 + j * 16 + col) * 64 + chko];
            #pragma unroll
            for (int i = 0; i < 4; i++)
                #pragma unroll
                for (int j = 0; j < 4; j++)
                    acc[i][j] = __builtin_amdgcn_mfma_f32_16x16x32_bf16(af[i], bfr[j], acc[i][j], 0, 0, 0);
        }
        __syncthreads();
    }

    #pragma unroll
    for (int i = 0; i < 4; i++) {
        int row = m0 + wr * 64 + i * 16 + quad * 4;
        #pragma unroll
        for (int j = 0; j < 4; j++) {
            int c = n0 + wc * 64 + j * 16 + col;
            #pragma unroll
            for (int r = 0; r < 4; r++) {
                float v = acc[i][j][r];
                if (OUT_BF16)
                    ((unsigned short*)Cout)[(size_t)(row + r) * N + c] = f2bf(v);
                else
                    ((float*)Cout)[(size_t)(row + r) * N + c] = v;
            }
        }
    }
}

// ---------------- RMS-norm (+scale) + RoPE, scatter to attention layouts ----------------
__global__ __launch_bounds__(256) void k_norm_rope(const unsigned short* __restrict__ qkv,
                                                   const int* __restrict__ spos,
                                                   const float* __restrict__ qscale,
                                                   const float* __restrict__ kscale,
                                                   unsigned short* __restrict__ qh,
                                                   unsigned short* __restrict__ kh,
                                                   unsigned short* __restrict__ vT) {
    const int t = blockIdx.x, slot = blockIdx.y, h = threadIdx.x;
    float val = bf2f(qkv[(size_t)t * QKV_COLS + slot * HD + h]);
    float ss = val * val;
    #pragma unroll
    for (int m = 1; m < 64; m <<= 1) ss += __shfl_xor(ss, m, 64);
    __shared__ float wsum[4];
    __shared__ float ybuf[256];
    if ((h & 63) == 0) wsum[h >> 6] = ss;
    __syncthreads();
    float tot = wsum[0] + wsum[1] + wsum[2] + wsum[3];
    float y = val * rsqrtf(tot * (1.0f / 256.0f) + 1e-6f);
    if (slot < 16) y *= (1.0f + qscale[h]);
    else if (slot < 24) y *= (1.0f + kscale[h]);

    if (slot < 24) {
        ybuf[h] = y;
        __syncthreads();
        int hh = h & 127;
        float fr = (float)hh * (1.0f / 128.0f);
        float ts = __expf(fr * 9.210340371976184f);   // 10000^fr
        float ang = (float)spos[t] / ts;
        float sn = __sinf(ang), cs = __cosf(ang);
        float other = ybuf[(h < 128) ? (h + 128) : (h - 128)];
        float outv = (h < 128) ? (y * cs - other * sn) : (y * cs + other * sn);
        if (slot < 16)
            qh[((size_t)slot * T_SEQ + t) * HD + h] = f2bf(outv);
        else
            kh[((size_t)(slot - 16) * T_SEQ + t) * HD + h] = f2bf(outv);
    } else {
        vT[((size_t)(slot - 24) * HD + h) * T_SEQ + t] = f2bf(y);
    }
}

// ---------------- flash attention v2 ----------------
__global__ __launch_bounds__(256) void k_attn(const unsigned short* __restrict__ qh,
                                              const unsigned short* __restrict__ kh,
                                              const unsigned short* __restrict__ vT,
                                              unsigned short* __restrict__ enc) {
    __shared__ unsigned short Ks[32 * 256];   // [s][k], 16B granules XOR-swizzled by (s&7)
    __shared__ unsigned short Vs[256 * 32];   // [h][s], 16B granules XOR-swizzled by (h&3)
    __shared__ unsigned short Pl[4][16 * 40]; // per-wave P round-trip, stride 40 kills conflicts

    const int tid = threadIdx.x;
    const int wave = tid >> 6, lane = tid & 63;
    const int col = lane & 15, quad = lane >> 4;
    const int kk = blockIdx.x;
    const int t0b = blockIdx.y * 32;
    const int headSel = wave & 1, rowSel = wave >> 1;
    const int n = kk * 2 + headSel;
    const int tw = t0b + rowSel * 16;

    const unsigned short* qp = qh + ((size_t)n * T_SEQ + tw) * HD;
    const unsigned short* kp = kh + (size_t)kk * T_SEQ * HD;
    const unsigned short* vp = vT + (size_t)kk * HD * T_SEQ;

    bf16x8 qf[8];
    #pragma unroll
    for (int c = 0; c < 8; c++)
        qf[c] = *(const bf16x8*)(qp + (size_t)col * HD + c * 32 + quad * 8);

    int preK[4], preV[4], ldsKo[4], ldsVo[4];
    #pragma unroll
    for (int i = 0; i < 4; i++) {
        int krow = 2 * (wave * 4 + i) + (lane >> 5);
        int kpos = lane & 31;
        preK[i] = krow * HD + ((kpos ^ (krow & 7)) * 8);
        ldsKo[i] = (wave * 4 + i) * 512;
        int vh = (wave * 4 + i) * 16 + (lane >> 2);
        int vpp = lane & 3;
        preV[i] = vh * T_SEQ + ((vpp ^ (vh & 3)) * 8);
        ldsVo[i] = (wave * 4 + i) * 512;
    }

    f32x4 o[16];
    #pragma unroll
    for (int h = 0; h < 16; h++) o[h] = (f32x4){0.f, 0.f, 0.f, 0.f};
    float lsum[4] = {0.f, 0.f, 0.f, 0.f};

    int s_begin = t0b - (WINDOW - 1);
    if (s_begin < 0) s_begin = 0;
    s_begin &= ~31;
    const int s_end = t0b + 32;

    for (int s0 = s_begin; s0 < s_end; s0 += 32) {
        #pragma unroll
        for (int i = 0; i < 4; i++)
            gl_lds16(kp + (size_t)s0 * HD + preK[i], &Ks[ldsKo[i]]);
        #pragma unroll
        for (int i = 0; i < 4; i++)
            gl_lds16(vp + (size_t)s0 + preV[i], &Vs[ldsVo[i]]);
        __syncthreads();

        f32x4 S0 = (f32x4){0.f, 0.f, 0.f, 0.f};
        f32x4 S1 = (f32x4){0.f, 0.f, 0.f, 0.f};
        #pragma unroll
        for (int c = 0; c < 8; c++) {
            bf16x8 kf = *(const bf16x8*)&Ks[(size_t)col * HD + (((c * 4 + quad) ^ (col & 7)) * 8)];
            S0 = __builtin_amdgcn_mfma_f32_16x16x32_bf16(qf[c], kf, S0, 0, 0, 0);
        }
        #pragma unroll
        for (int c = 0; c < 8; c++) {
            bf16x8 kf = *(const bf16x8*)&Ks[(size_t)(16 + col) * HD + (((c * 4 + quad) ^ (col & 7)) * 8)];
            S1 = __builtin_amdgcn_mfma_f32_16x16x32_bf16(qf[c], kf, S1, 0, 0, 0);
        }

        #pragma unroll
        for (int r = 0; r < 4; r++) {
            int t = tw + quad * 4 + r;
            int sA = s0 + col, sB = sA + 16;
            bool vA = (sA <= t) && (sA >= t - (WINDOW - 1));
            bool vB = (sB <= t) && (sB >= t - (WINDOW - 1));
            float eA = __expf(S0[r] * (2.0f / SOFT_CAP));
            float eB = __expf(S1[r] * (2.0f / SOFT_CAP));
            float rA = __builtin_amdgcn_rcpf(eA + 1.0f);
            float rB = __builtin_amdgcn_rcpf(eB + 1.0f);
            float pA = __expf(SOFT_CAP - 2.0f * SOFT_CAP * rA);
            float pB = __expf(SOFT_CAP - 2.0f * SOFT_CAP * rB);
            pA = vA ? pA : 0.0f;
            pB = vB ? pB : 0.0f;
            lsum[r] += pA + pB;
            Pl[wave][(quad * 4 + r) * 40 + col] = f2bf(pA);
            Pl[wave][(quad * 4 + r) * 40 + 16 + col] = f2bf(pB);
        }

        bf16x8 pf = *(const bf16x8*)&Pl[wave][col * 40 + quad * 8];

        #pragma unroll
        for (int ht = 0; ht < 16; ht++) {
            int h = ht * 16 + col;
            bf16x8 vf = *(const bf16x8*)&Vs[(size_t)h * 32 + ((quad ^ (h & 3)) * 8)];
            o[ht] = __builtin_amdgcn_mfma_f32_16x16x32_bf16(pf, vf, o[ht], 0, 0, 0);
        }
        __syncthreads();
    }

    #pragma unroll
    for (int r = 0; r < 4; r++) {
        #pragma unroll
        for (int m = 1; m < 16; m <<= 1)
            lsum[r] += __shfl_xor(lsum[r], m, 16);
        lsum[r] = 1.0f / lsum[r];
    }
    #pragma unroll
    for (int ht = 0; ht < 16; ht++) {
        #pragma unroll
        for (int r = 0; r < 4; r++) {
            int t = tw + quad * 4 + r;
            enc[(size_t)t * (NQ * HD) + n * HD + ht * 16 + col] = f2bf(o[ht][r] * lsum[r]);
        }
    }
}

extern "C" void kernel_launch(void* const* d_in, const int* in_sizes, int n_in,
                              void* d_out, int out_size, void* d_ws, size_t ws_size,
                              hipStream_t stream) {
    const float* x       = (const float*)d_in[0];
    const int*   spos    = (const int*)d_in[1];
    const float* w_q     = (const float*)d_in[3];
    const float* w_kv    = (const float*)d_in[4];
    const float* w_out   = (const float*)d_in[5];
    const float* q_scale = (const float*)d_in[6];
    const float* k_scale = (const float*)d_in[7];
    float* out = (float*)d_out;

    char* ws = (char*)d_ws;
    unsigned short* xb     = (unsigned short*)(ws + 0);          // 2048x3072 bf16
    unsigned short* wT     = (unsigned short*)(ws + 12582912);   // 8192x3072 bf16
    unsigned short* wToutb = (unsigned short*)(ws + 12582912);   // 3072x4096 bf16 (reuse)
    unsigned short* encb   = (unsigned short*)(ws + 37748736);   // 2048x4096 bf16 (reuse)
    unsigned short* qkv    = (unsigned short*)(ws + 62914560);   // 2048x8192 bf16
    unsigned short* qh     = (unsigned short*)(ws + 96468992);   // 16x2048x256 bf16
    unsigned short* kh     = (unsigned short*)(ws + 113246208);  // 8x2048x256 bf16
    unsigned short* vT     = (unsigned short*)(ws + 121634816);  // 8x256x2048 bf16

    k_convert<<<dim3((T_SEQ * D_MODEL / 4 + 255) / 256), dim3(256), 0, stream>>>(
        x, xb, T_SEQ * D_MODEL / 4);
    k_transpose_bf16<<<dim3(HD / 32, D_MODEL / 32, NQ), dim3(32, 8), 0, stream>>>(
        w_q, wT, D_MODEL, HD);
    k_transpose_bf16<<<dim3(HD / 32, D_MODEL / 32, 16), dim3(32, 8), 0, stream>>>(
        w_kv, wT + (size_t)4096 * D_MODEL, D_MODEL, HD);
    k_gemm_nt<1><<<dim3((T_SEQ / 128) * (QKV_COLS / 128)), dim3(256), 0, stream>>>(
        xb, wT, qkv, T_SEQ, QKV_COLS, D_MODEL);
    k_transpose_bf16<<<dim3(D_MODEL / 32, 4096 / 32, 1), dim3(32, 8), 0, stream>>>(
        w_out, wToutb, 4096, D_MODEL);
    k_norm_rope<<<dim3(T_SEQ, NHEADS_TOT), dim3(256), 0, stream>>>(
        qkv, spos, q_scale, k_scale, qh, kh, vT);
    k_attn<<<dim3(NKV, T_SEQ / 32), dim3(256), 0, stream>>>(qh, kh, vT, encb);
    k_gemm_nt<0><<<dim3((T_SEQ / 128) * (D_MODEL / 128)), dim3(256), 0, stream>>>(
        encb, wToutb, out, T_SEQ, D_MODEL, NQ * HD);
}

// Round 4
// 550.103 us; speedup vs baseline: 1.4973x; 1.0160x over previous
//
#include <hip/hip_runtime.h>
#include <math.h>

// Problem constants
#define T_SEQ 2048
#define D_MODEL 3072
#define NQ 16
#define NKV 8
#define HD 256
#define NHEADS_TOT 32          // 16 q + 8 k + 8 v projection "slots"
#define QKV_COLS 8192          // 32 * 256
#define SOFT_CAP 50.0f
#define WINDOW 1024
#define K_MASK -2.3819763e38f

typedef __attribute__((ext_vector_type(8))) short bf16x8;
typedef __attribute__((ext_vector_type(4))) float f32x4;

__device__ __forceinline__ unsigned short f2bf(float f) {
    union { float f; unsigned u; } v; v.f = f;
    unsigned r = (v.u + 0x7fff + ((v.u >> 16) & 1)) >> 16;
    return (unsigned short)r;
}
__device__ __forceinline__ float bf2f(unsigned short u) {
    union { unsigned u; float f; } v; v.u = ((unsigned)u) << 16;
    return v.f;
}

__device__ __forceinline__ void gl_lds16(const unsigned short* g, unsigned short* l) {
    __builtin_amdgcn_global_load_lds(
        (const __attribute__((address_space(1))) void*)g,
        (__attribute__((address_space(3))) void*)l, 16, 0, 0);
}

// ---------------- convert f32 -> bf16 (flat) ----------------
__global__ __launch_bounds__(256) void k_convert(const float* __restrict__ src,
                                                 unsigned short* __restrict__ dst, int n4) {
    int i = blockIdx.x * 256 + threadIdx.x;
    if (i >= n4) return;
    float4 v = ((const float4*)src)[i];
    ushort4 o;
    o.x = f2bf(v.x); o.y = f2bf(v.y); o.z = f2bf(v.z); o.w = f2bf(v.w);
    ((ushort4*)dst)[i] = o;
}

// ---------------- batched transpose+convert: (batch,R,C) f32 -> (batch,C,R) bf16 ----------------
__global__ __launch_bounds__(256) void k_transpose_bf16(const float* __restrict__ src,
                                                        unsigned short* __restrict__ dst,
                                                        int R, int C) {
    __shared__ float tile[32][33];
    int b = blockIdx.z;
    src += (size_t)b * R * C;
    dst += (size_t)b * R * C;
    int c0 = blockIdx.x * 32, r0 = blockIdx.y * 32;
    int tx = threadIdx.x, ty = threadIdx.y;   // 32 x 8
    #pragma unroll
    for (int i = ty; i < 32; i += 8)
        tile[i][tx] = src[(size_t)(r0 + i) * C + c0 + tx];
    __syncthreads();
    #pragma unroll
    for (int i = ty; i < 32; i += 8)
        dst[(size_t)(c0 + i) * R + r0 + tx] = f2bf(tile[tx][i]);
}

// ---------------- bf16 transpose: vh (8, T, H) -> vT (8, H, T) ----------------
__global__ __launch_bounds__(256) void k_transpose_v(const unsigned short* __restrict__ src,
                                                     unsigned short* __restrict__ dst) {
    __shared__ unsigned short tile[32][34];
    int kk = blockIdx.z;
    src += (size_t)kk * T_SEQ * HD;
    dst += (size_t)kk * HD * T_SEQ;
    int h0 = blockIdx.x * 32, t0 = blockIdx.y * 32;
    int tx = threadIdx.x, ty = threadIdx.y;   // 32 x 8
    #pragma unroll
    for (int i = ty; i < 32; i += 8)
        tile[i][tx] = src[(size_t)(t0 + i) * HD + h0 + tx];
    __syncthreads();
    #pragma unroll
    for (int i = ty; i < 32; i += 8)
        dst[(size_t)(h0 + i) * T_SEQ + t0 + tx] = tile[tx][i];
}

// ---------------- NT GEMM: C[M,N] = A[M,K] * BT[N,K]^T   (bf16 in, f32 acc) ----------------
// 128x128 block tile, BK=64, 4 waves each 64x64. XCD-aware 1-D grid remap.
template <int OUT_BF16>
__global__ __launch_bounds__(256) void k_gemm_nt(const unsigned short* __restrict__ A,
                                                 const unsigned short* __restrict__ BT,
                                                 void* __restrict__ Cout,
                                                 int M, int N, int Kd) {
    __shared__ unsigned short As[128 * 64];
    __shared__ unsigned short Bs[128 * 64];
    const int tid = threadIdx.x;
    const int wave = tid >> 6, lane = tid & 63;
    const int col = lane & 15, quad = lane >> 4;
    const int wr = wave >> 1, wc = wave & 1;

    const int gx = M >> 7;
    int p = blockIdx.x;
    int xcd = p & 7, q = p >> 3;
    int i_t = q % gx, jj = q / gx;
    int j_t = jj * 8 + xcd;
    const int m0 = i_t * 128, n0 = j_t * 128;

    const int sub = wave & 1, isB = wave >> 1;
    const unsigned short* srcBase = isB ? (BT + (size_t)(n0 + sub * 64) * Kd)
                                        : (A + (size_t)(m0 + sub * 64) * Kd);
    unsigned short* ldsBase = (isB ? Bs : As) + sub * 64 * 64;
    const int lrow = lane >> 3, lchk = lane & 7;
    int soff[8];
    #pragma unroll
    for (int s = 0; s < 8; s++) {
        int r = s * 8 + lrow;
        soff[s] = r * Kd + ((lchk ^ (r & 7)) * 8);
    }

    f32x4 acc[4][4];
    #pragma unroll
    for (int i = 0; i < 4; i++)
        #pragma unroll
        for (int j = 0; j < 4; j++)
            acc[i][j] = (f32x4){0.f, 0.f, 0.f, 0.f};

    const int sw = col & 7;

    for (int k0 = 0; k0 < Kd; k0 += 64) {
        #pragma unroll
        for (int s = 0; s < 8; s++)
            gl_lds16(srcBase + soff[s] + k0, ldsBase + s * 512);
        __syncthreads();

        #pragma unroll
        for (int kk = 0; kk < 2; kk++) {
            bf16x8 af[4], bfr[4];
            const int chko = ((kk * 4 + quad) ^ sw) * 8;
            #pragma unroll
            for (int i = 0; i < 4; i++)
                af[i] = *(const bf16x8*)&As[(wr * 64 + i * 16 + col) * 64 + chko];
            #pragma unroll
            for (int j = 0; j < 4; j++)
                bfr[j] = *(const bf16x8*)&Bs[(wc * 64 + j * 16 + col) * 64 + chko];
            #pragma unroll
            for (int i = 0; i < 4; i++)
                #pragma unroll
                for (int j = 0; j < 4; j++)
                    acc[i][j] = __builtin_amdgcn_mfma_f32_16x16x32_bf16(af[i], bfr[j], acc[i][j], 0, 0, 0);
        }
        __syncthreads();
    }

    #pragma unroll
    for (int i = 0; i < 4; i++) {
        int row = m0 + wr * 64 + i * 16 + quad * 4;
        #pragma unroll
        for (int j = 0; j < 4; j++) {
            int c = n0 + wc * 64 + j * 16 + col;
            #pragma unroll
            for (int r = 0; r < 4; r++) {
                float v = acc[i][j][r];
                if (OUT_BF16)
                    ((unsigned short*)Cout)[(size_t)(row + r) * N + c] = f2bf(v);
                else
                    ((float*)Cout)[(size_t)(row + r) * N + c] = v;
            }
        }
    }
}

// ---------------- RMS-norm (+scale) + RoPE ----------------
// v path now writes COALESCED vh[kk][t][h] (transpose done by k_transpose_v).
__global__ __launch_bounds__(256) void k_norm_rope(const unsigned short* __restrict__ qkv,
                                                   const int* __restrict__ spos,
                                                   const float* __restrict__ qscale,
                                                   const float* __restrict__ kscale,
                                                   unsigned short* __restrict__ qh,
                                                   unsigned short* __restrict__ kh,
                                                   unsigned short* __restrict__ vh) {
    const int t = blockIdx.x, slot = blockIdx.y, h = threadIdx.x;
    float val = bf2f(qkv[(size_t)t * QKV_COLS + slot * HD + h]);
    float ss = val * val;
    #pragma unroll
    for (int m = 1; m < 64; m <<= 1) ss += __shfl_xor(ss, m, 64);
    __shared__ float wsum[4];
    __shared__ float ybuf[256];
    if ((h & 63) == 0) wsum[h >> 6] = ss;
    __syncthreads();
    float tot = wsum[0] + wsum[1] + wsum[2] + wsum[3];
    float y = val * rsqrtf(tot * (1.0f / 256.0f) + 1e-6f);
    if (slot < 16) y *= (1.0f + qscale[h]);
    else if (slot < 24) y *= (1.0f + kscale[h]);

    if (slot < 24) {
        ybuf[h] = y;
        __syncthreads();
        int hh = h & 127;
        float fr = (float)hh * (1.0f / 128.0f);
        float ts = __expf(fr * 9.210340371976184f);   // 10000^fr
        float ang = (float)spos[t] / ts;
        float sn = __sinf(ang), cs = __cosf(ang);
        float other = ybuf[(h < 128) ? (h + 128) : (h - 128)];
        float outv = (h < 128) ? (y * cs - other * sn) : (y * cs + other * sn);
        if (slot < 16)
            qh[((size_t)slot * T_SEQ + t) * HD + h] = f2bf(outv);
        else
            kh[((size_t)(slot - 16) * T_SEQ + t) * HD + h] = f2bf(outv);
    } else {
        vh[((size_t)(slot - 24) * T_SEQ + t) * HD + h] = f2bf(y);
    }
}

// ---------------- flash attention v3: s-tile = 64 (half the barrier drains) ----------------
// Block: 4 waves. blockIdx.x = kv head (8), blockIdx.y = 32-row t tile (64).
// Accumulation order per lane identical to the 32-step version (two 32-chunks in sequence).
__global__ __launch_bounds__(256) void k_attn(const unsigned short* __restrict__ qh,
                                              const unsigned short* __restrict__ kh,
                                              const unsigned short* __restrict__ vT,
                                              unsigned short* __restrict__ enc) {
    __shared__ unsigned short Ks[64 * 256];   // [s][k], 16B granules XOR-swizzled by (s&7)
    __shared__ unsigned short Vs[256 * 64];   // [h][s], 16B granules XOR-swizzled by (h&7)
    __shared__ unsigned short Pl[4][16 * 72]; // per-wave P round-trip, 16B-aligned stride

    const int tid = threadIdx.x;
    const int wave = tid >> 6, lane = tid & 63;
    const int col = lane & 15, quad = lane >> 4;
    const int kk = blockIdx.x;
    const int t0b = blockIdx.y * 32;
    const int headSel = wave & 1, rowSel = wave >> 1;
    const int n = kk * 2 + headSel;
    const int tw = t0b + rowSel * 16;

    const unsigned short* qp = qh + ((size_t)n * T_SEQ + tw) * HD;
    const unsigned short* kp = kh + (size_t)kk * T_SEQ * HD;
    const unsigned short* vp = vT + (size_t)kk * HD * T_SEQ;

    bf16x8 qf[8];
    #pragma unroll
    for (int c = 0; c < 8; c++)
        qf[c] = *(const bf16x8*)(qp + (size_t)col * HD + c * 32 + quad * 8);

    // staging offsets: K tile 64x256 (8 insts), V tile 256x64 (8 insts)
    int preK[8], preV[8];
    #pragma unroll
    for (int i = 0; i < 8; i++) {
        int j = wave * 8 + i;               // 0..31
        int krow = 2 * j + (lane >> 5);     // 0..63
        int kg = lane & 31;
        preK[i] = krow * HD + ((kg ^ (krow & 7)) * 8);
        int vrow = 8 * j + (lane >> 3);     // 0..255
        int vg = lane & 7;
        preV[i] = vrow * T_SEQ + ((vg ^ (vrow & 7)) * 8);
    }

    f32x4 o[16];
    #pragma unroll
    for (int h = 0; h < 16; h++) o[h] = (f32x4){0.f, 0.f, 0.f, 0.f};
    float lsum[4] = {0.f, 0.f, 0.f, 0.f};

    int s_begin = t0b - (WINDOW - 1);
    if (s_begin < 0) s_begin = 0;
    s_begin &= ~63;
    const int s_end = t0b + 32;

    for (int s0 = s_begin; s0 < s_end; s0 += 64) {
        #pragma unroll
        for (int i = 0; i < 8; i++)
            gl_lds16(kp + (size_t)s0 * HD + preK[i], &Ks[(wave * 8 + i) * 512]);
        #pragma unroll
        for (int i = 0; i < 8; i++)
            gl_lds16(vp + (size_t)s0 + preV[i], &Vs[(wave * 8 + i) * 512]);
        __syncthreads();

        // QK^T: 4 groups of 16 s-columns
        f32x4 S[4];
        #pragma unroll
        for (int g = 0; g < 4; g++) S[g] = (f32x4){0.f, 0.f, 0.f, 0.f};
        #pragma unroll
        for (int g = 0; g < 4; g++)
            #pragma unroll
            for (int c = 0; c < 8; c++) {
                bf16x8 kf = *(const bf16x8*)&Ks[(size_t)(g * 16 + col) * 256 +
                                                (((c * 4 + quad) ^ (col & 7)) * 8)];
                S[g] = __builtin_amdgcn_mfma_f32_16x16x32_bf16(qf[c], kf, S[g], 0, 0, 0);
            }

        // softcap + exp (m=0): p = exp(50 - 100/(exp(S/25)+1)), masked
        #pragma unroll
        for (int r = 0; r < 4; r++) {
            int t = tw + quad * 4 + r;
            float p[4];
            #pragma unroll
            for (int g = 0; g < 4; g++) {
                int s = s0 + g * 16 + col;
                bool vld = (s <= t) && (s >= t - (WINDOW - 1));
                float e = __expf(S[g][r] * (2.0f / SOFT_CAP));
                float rc = __builtin_amdgcn_rcpf(e + 1.0f);
                float pv = __expf(SOFT_CAP - 2.0f * SOFT_CAP * rc);
                p[g] = vld ? pv : 0.0f;
                Pl[wave][(quad * 4 + r) * 72 + g * 16 + col] = f2bf(p[g]);
            }
            lsum[r] += p[0] + p[1];   // same pairing/order as two 32-steps
            lsum[r] += p[2] + p[3];
        }

        bf16x8 pf0 = *(const bf16x8*)&Pl[wave][col * 72 + quad * 8];
        bf16x8 pf1 = *(const bf16x8*)&Pl[wave][col * 72 + 32 + quad * 8];

        // PV: O += P * V  (s-chunks in order for bit-identical accumulation)
        #pragma unroll
        for (int ht = 0; ht < 16; ht++) {
            int h = ht * 16 + col;
            bf16x8 vf0 = *(const bf16x8*)&Vs[(size_t)h * 64 + ((quad ^ (h & 7)) * 8)];
            bf16x8 vf1 = *(const bf16x8*)&Vs[(size_t)h * 64 + (((quad + 4) ^ (h & 7)) * 8)];
            o[ht] = __builtin_amdgcn_mfma_f32_16x16x32_bf16(pf0, vf0, o[ht], 0, 0, 0);
            o[ht] = __builtin_amdgcn_mfma_f32_16x16x32_bf16(pf1, vf1, o[ht], 0, 0, 0);
        }
        __syncthreads();
    }

    #pragma unroll
    for (int r = 0; r < 4; r++) {
        #pragma unroll
        for (int m = 1; m < 16; m <<= 1)
            lsum[r] += __shfl_xor(lsum[r], m, 16);
        lsum[r] = 1.0f / lsum[r];
    }
    #pragma unroll
    for (int ht = 0; ht < 16; ht++) {
        #pragma unroll
        for (int r = 0; r < 4; r++) {
            int t = tw + quad * 4 + r;
            enc[(size_t)t * (NQ * HD) + n * HD + ht * 16 + col] = f2bf(o[ht][r] * lsum[r]);
        }
    }
}

extern "C" void kernel_launch(void* const* d_in, const int* in_sizes, int n_in,
                              void* d_out, int out_size, void* d_ws, size_t ws_size,
                              hipStream_t stream) {
    const float* x       = (const float*)d_in[0];
    const int*   spos    = (const int*)d_in[1];
    const float* w_q     = (const float*)d_in[3];
    const float* w_kv    = (const float*)d_in[4];
    const float* w_out   = (const float*)d_in[5];
    const float* q_scale = (const float*)d_in[6];
    const float* k_scale = (const float*)d_in[7];
    float* out = (float*)d_out;

    char* ws = (char*)d_ws;
    unsigned short* xb     = (unsigned short*)(ws + 0);          // 2048x3072 bf16 (dead after gemm1)
    unsigned short* vh     = (unsigned short*)(ws + 0);          // 8x2048x256 bf16 (reuses xb)
    unsigned short* wT     = (unsigned short*)(ws + 12582912);   // 8192x3072 bf16
    unsigned short* wToutb = (unsigned short*)(ws + 12582912);   // 3072x4096 bf16 (reuse)
    unsigned short* encb   = (unsigned short*)(ws + 37748736);   // 2048x4096 bf16 (reuse)
    unsigned short* qkv    = (unsigned short*)(ws + 62914560);   // 2048x8192 bf16
    unsigned short* qh     = (unsigned short*)(ws + 96468992);   // 16x2048x256 bf16
    unsigned short* kh     = (unsigned short*)(ws + 113246208);  // 8x2048x256 bf16
    unsigned short* vT     = (unsigned short*)(ws + 121634816);  // 8x256x2048 bf16

    k_convert<<<dim3((T_SEQ * D_MODEL / 4 + 255) / 256), dim3(256), 0, stream>>>(
        x, xb, T_SEQ * D_MODEL / 4);
    k_transpose_bf16<<<dim3(HD / 32, D_MODEL / 32, NQ), dim3(32, 8), 0, stream>>>(
        w_q, wT, D_MODEL, HD);
    k_transpose_bf16<<<dim3(HD / 32, D_MODEL / 32, 16), dim3(32, 8), 0, stream>>>(
        w_kv, wT + (size_t)4096 * D_MODEL, D_MODEL, HD);
    k_gemm_nt<1><<<dim3((T_SEQ / 128) * (QKV_COLS / 128)), dim3(256), 0, stream>>>(
        xb, wT, qkv, T_SEQ, QKV_COLS, D_MODEL);
    k_transpose_bf16<<<dim3(D_MODEL / 32, 4096 / 32, 1), dim3(32, 8), 0, stream>>>(
        w_out, wToutb, 4096, D_MODEL);
    k_norm_rope<<<dim3(T_SEQ, NHEADS_TOT), dim3(256), 0, stream>>>(
        qkv, spos, q_scale, k_scale, qh, kh, vh);
    k_transpose_v<<<dim3(HD / 32, T_SEQ / 32, NKV), dim3(32, 8), 0, stream>>>(vh, vT);
    k_attn<<<dim3(NKV, T_SEQ / 32), dim3(256), 0, stream>>>(qh, kh, vT, encb);
    k_gemm_nt<0><<<dim3((T_SEQ / 128) * (D_MODEL / 128)), dim3(256), 0, stream>>>(
        encb, wToutb, out, T_SEQ, D_MODEL, NQ * HD);
}